// Round 13
// baseline (1093.148 us; speedup 1.0000x reference)
//
#include <hip/hip_runtime.h>
#include <math.h>

#define NN 100000
#define EE 1600000
#define BB 64
#define CAP 48   // max in-degree; deg ~ Poisson(16), P(deg>=48) ~ 2e-10

typedef __attribute__((ext_vector_type(8))) short bf16x8;   // 8 bf16 (4 VGPRs)
typedef __attribute__((ext_vector_type(4))) float f32x4;    // 4 fp32 acc

__device__ __forceinline__ float lrelu(float v) { return v > 0.f ? v : 0.2f * v; }

// ---------- temporal conv: x[N,1,35] -> h0[N,128] (16 nodes x 16 thr) ----------
__global__ __launch_bounds__(256) void conv_kernel(
    const float* __restrict__ x,
    const float* __restrict__ w1, const float* __restrict__ b1,
    const float* __restrict__ w2, const float* __restrict__ b2,
    float* __restrict__ h0)
{
  __shared__ float s_x[16 * 35];
  __shared__ float s_c1[16 * 49];
  __shared__ float s_w2[16 * 49];
  __shared__ float s_w1[48], s_b1[16], s_b2[16];
  int tid = threadIdx.x;
  int n0 = blockIdx.x * 16;
  for (int i = tid; i < 16 * 35; i += 256) s_x[i] = x[(size_t)n0 * 35 + i];
  if (tid < 48) s_w1[tid] = w1[tid];
  if (tid < 16) { s_b1[tid] = b1[tid]; s_b2[tid] = b2[tid]; }
  for (int i = tid; i < 768; i += 256) s_w2[(i / 48) * 49 + (i % 48)] = w2[i];
  __syncthreads();

  int node = tid >> 4;
  int lane = tid & 15;
  const float* row = s_x + node * 35;
  float* c1n = s_c1 + node * 49;
  float acc8[8];

  for (int t = 0; t < 8; ++t) {
#pragma unroll
    for (int k = 0; k < 3; ++k) {
      int base = 4 * t + 2 * k;
      float a = s_b1[lane] + s_w1[lane * 3] * row[base]
                           + s_w1[lane * 3 + 1] * row[base + 1]
                           + s_w1[lane * 3 + 2] * row[base + 2];
      c1n[lane * 3 + k] = a > 0.f ? a : 0.f;
    }
    __syncthreads();
    float acc = s_b2[lane];
    const float* w2r = s_w2 + lane * 49;
#pragma unroll
    for (int i = 0; i < 48; ++i) acc += w2r[i] * c1n[i];
    acc8[t] = fmaxf(acc, 0.f);
    __syncthreads();
  }

  float* o = h0 + (size_t)(n0 + node) * 128 + lane * 8;
  float4 o0 = { acc8[0], acc8[1], acc8[2], acc8[3] };
  float4 o1 = { acc8[4], acc8[5], acc8[6], acc8[7] };
  *(float4*)o = o0;
  *(float4*)(o + 4) = o1;
}

// ---------- padded-CSR scatter: 1 edge/thread (measured-best shape) ----------
__global__ void scatter_pad(const int* __restrict__ src, const int* __restrict__ dst,
                            const float* __restrict__ ea,
                            int* __restrict__ cursor, int2* __restrict__ pack)
{
  int e = blockIdx.x * blockDim.x + threadIdx.x;
  if (e >= EE) return;
  int d = dst[e];
  int pos = atomicAdd(cursor + d, 1);
  if (pos < CAP)
    pack[(size_t)d * CAP + pos] = make_int2(src[e], __float_as_int(ea[e]));
}

// ---------- W prep: [Wl|Wr] fp32 -> transposed bf16 hi/lo  Wt[n(256)][k(128)] ----------
__global__ __launch_bounds__(128) void prep_w(
    const float* __restrict__ Wl0, const float* __restrict__ Wr0,
    const float* __restrict__ Wl1, const float* __restrict__ Wr1,
    unsigned short* __restrict__ wtH, unsigned short* __restrict__ wtL)
{
  int bx = blockIdx.x;              // layer*256 + n
  int layer = bx >> 8;
  int n = bx & 255;
  const float* W = (layer == 0) ? ((n < 128) ? Wl0 : Wr0)
                                : ((n < 128) ? Wl1 : Wr1);
  int nn = n & 127;
  int k = threadIdx.x;
  float v = W[k * 128 + nn];
  unsigned b = __float_as_uint(v);
  unsigned short hi = (unsigned short)(b >> 16);
  float hv = __uint_as_float(b & 0xffff0000u);
  float lv = v - hv;                               // exact
  unsigned short lo = (unsigned short)(__float_as_uint(lv) >> 16);
  wtH[(size_t)bx * 128 + k] = hi;
  wtL[(size_t)bx * 128 + k] = lo;
}

// ---------- MFMA dual GEMM (bf16x3 split = fp32-accurate) ----------
// 782 blocks x 256 thr; wave w owns rows blk*128 + w*32 .. +32 (2 m-tiles), all 256 cols.
__global__ __launch_bounds__(256) void gemm_mfma(
    const float* __restrict__ A,
    const unsigned short* __restrict__ wtH, const unsigned short* __restrict__ wtL,
    float* __restrict__ Cl, float* __restrict__ Cr)
{
  int tid = threadIdx.x;
  int l = tid & 63;
  int w = tid >> 6;
  int lm = l & 15;                 // m (A) / n (B) / col (C) within tile
  int lk = (l >> 4) * 8;           // k chunk offset within 32
  int rowA = blockIdx.x * 128 + w * 32 + lm;
  int rowB = rowA + 16;
  int rA = rowA < NN ? rowA : 0;   // clamp loads; stores guarded
  int rB = rowB < NN ? rowB : 0;

  f32x4 accA[16], accB[16];
  f32x4 z = { 0.f, 0.f, 0.f, 0.f };
#pragma unroll
  for (int nt = 0; nt < 16; ++nt) { accA[nt] = z; accB[nt] = z; }

  for (int k0 = 0; k0 < 128; k0 += 32) {
    int kb = k0 + lk;
    // load A rows as fp32, split to bf16 hi/lo in-register
    const float* pA = A + (size_t)rA * 128 + kb;
    const float* pB = A + (size_t)rB * 128 + kb;
    float4 a0 = *(const float4*)pA;
    float4 a1 = *(const float4*)(pA + 4);
    float4 b0 = *(const float4*)pB;
    float4 b1 = *(const float4*)(pB + 4);
    float va[8] = { a0.x, a0.y, a0.z, a0.w, a1.x, a1.y, a1.z, a1.w };
    float vb[8] = { b0.x, b0.y, b0.z, b0.w, b1.x, b1.y, b1.z, b1.w };
    bf16x8 aAh, aAl, aBh, aBl;
#pragma unroll
    for (int j = 0; j < 8; ++j) {
      unsigned ba = __float_as_uint(va[j]);
      aAh[j] = (short)(ba >> 16);
      float laf = va[j] - __uint_as_float(ba & 0xffff0000u);
      aAl[j] = (short)(__float_as_uint(laf) >> 16);
      unsigned bb = __float_as_uint(vb[j]);
      aBh[j] = (short)(bb >> 16);
      float lbf = vb[j] - __uint_as_float(bb & 0xffff0000u);
      aBl[j] = (short)(__float_as_uint(lbf) >> 16);
    }
#pragma unroll 4
    for (int nt = 0; nt < 16; ++nt) {
      const unsigned short* ph = wtH + (size_t)(nt * 16 + lm) * 128 + kb;
      const unsigned short* pl = wtL + (size_t)(nt * 16 + lm) * 128 + kb;
      bf16x8 bh = *(const bf16x8*)ph;
      bf16x8 bl = *(const bf16x8*)pl;
      accA[nt] = __builtin_amdgcn_mfma_f32_16x16x32_bf16(aAh, bh, accA[nt], 0, 0, 0);
      accA[nt] = __builtin_amdgcn_mfma_f32_16x16x32_bf16(aAh, bl, accA[nt], 0, 0, 0);
      accA[nt] = __builtin_amdgcn_mfma_f32_16x16x32_bf16(aAl, bh, accA[nt], 0, 0, 0);
      accB[nt] = __builtin_amdgcn_mfma_f32_16x16x32_bf16(aBh, bh, accB[nt], 0, 0, 0);
      accB[nt] = __builtin_amdgcn_mfma_f32_16x16x32_bf16(aBh, bl, accB[nt], 0, 0, 0);
      accB[nt] = __builtin_amdgcn_mfma_f32_16x16x32_bf16(aBl, bh, accB[nt], 0, 0, 0);
    }
  }

  // epilogue: C/D layout col=lane&15, row=(lane>>4)*4+reg  [m89-verified]
  int mbase = blockIdx.x * 128 + w * 32 + (l >> 4) * 4;
#pragma unroll
  for (int nt = 0; nt < 16; ++nt) {
    int col = nt * 16 + lm;
    float* Cb = (col < 128) ? Cl : Cr;
    int cc = col & 127;
#pragma unroll
    for (int r = 0; r < 4; ++r) {
      int ra2 = mbase + r;
      if (ra2 < NN) Cb[(size_t)ra2 * 128 + cc] = accA[nt][r];
      int rb2 = ra2 + 16;
      if (rb2 < NN) Cb[(size_t)rb2 * 128 + cc] = accB[nt][r];
    }
  }
}

// ---------- fused GAT node kernel ----------
// 32 lanes/node, log2-domain logits (exp2), 4-edge blocks with 1-ahead pipeline
__device__ __forceinline__ float edge_logit(float4 msg, float w,
                                            float4 hrd, float4 we4, float4 at4)
{
  float s0 = lrelu(fmaf(w, we4.x, hrd.x) + msg.x);
  float s1 = lrelu(fmaf(w, we4.y, hrd.y) + msg.y);
  float s2 = lrelu(fmaf(w, we4.z, hrd.z) + msg.z);
  float s3 = lrelu(fmaf(w, we4.w, hrd.w) + msg.w);
  float p = fmaf(s0, at4.x, fmaf(s1, at4.y, fmaf(s2, at4.z, s3 * at4.w)));
  p += __shfl_xor(p, 1, 8);
  p += __shfl_xor(p, 2, 8);
  p += __shfl_xor(p, 4, 8);
  return p;
}

__global__ __launch_bounds__(256) void gat_node_kernel(
    const int* __restrict__ cnt_arr, const int2* __restrict__ pack,
    const float* __restrict__ hl, const float* __restrict__ hr,
    const float* __restrict__ We, const float* __restrict__ att,
    const float* __restrict__ bias, float* __restrict__ out)
{
  int n = blockIdx.x * 8 + (threadIdx.x >> 5);
  if (n >= NN) return;
  int lq = threadIdx.x & 31;
  int j = lq * 4;
  float4 hrd = *(const float4*)(hr + (size_t)n * 128 + j);
  float4 we4 = *(const float4*)(We + j);
  float4 at4 = *(const float4*)(att + j);
  const float RLN2 = 1.44269504088896340736f;
  at4.x *= RLN2; at4.y *= RLN2; at4.z *= RLN2; at4.w *= RLN2;

  int cnt = cnt_arr[n]; if (cnt > CAP) cnt = CAP;
  const int2* p = pack + (size_t)n * CAP;

  float m = -INFINITY, l = 0.f, wsum = 0.f;
  float4 acc = { 0.f, 0.f, 0.f, 0.f };

  int nb = cnt >> 2;
  int4 ca, cb;
  float4 nr1, nr2, nr3, nr4;
  if (nb > 0) {
    const int4* p4 = (const int4*)p;
    ca = p4[0]; cb = p4[1];
    nr1 = *(const float4*)(hl + (size_t)ca.x * 128 + j);
    nr2 = *(const float4*)(hl + (size_t)ca.z * 128 + j);
    nr3 = *(const float4*)(hl + (size_t)cb.x * 128 + j);
    nr4 = *(const float4*)(hl + (size_t)cb.z * 128 + j);
  }
  for (int b = 0; b < nb; ++b) {
    int4 da = ca, db = cb;
    float4 m1 = nr1, m2 = nr2, m3 = nr3, m4 = nr4;
    if (b + 1 < nb) {
      const int4* p4 = (const int4*)(p + (b + 1) * 4);
      ca = p4[0]; cb = p4[1];
      nr1 = *(const float4*)(hl + (size_t)ca.x * 128 + j);
      nr2 = *(const float4*)(hl + (size_t)ca.z * 128 + j);
      nr3 = *(const float4*)(hl + (size_t)cb.x * 128 + j);
      nr4 = *(const float4*)(hl + (size_t)cb.z * 128 + j);
    }
    float w1 = __int_as_float(da.y), w2 = __int_as_float(da.w);
    float w3 = __int_as_float(db.y), w4 = __int_as_float(db.w);
    wsum += (w1 + w2) + (w3 + w4);
    float p1 = edge_logit(m1, w1, hrd, we4, at4);
    float p2 = edge_logit(m2, w2, hrd, we4, at4);
    float p3 = edge_logit(m3, w3, hrd, we4, at4);
    float p4v = edge_logit(m4, w4, hrd, we4, at4);
    float mn = fmaxf(fmaxf(m, fmaxf(p1, p2)), fmaxf(p3, p4v));
    float sc = exp2f(m - mn);
    float t1 = exp2f(p1 - mn);
    float t2 = exp2f(p2 - mn);
    float t3 = exp2f(p3 - mn);
    float t4 = exp2f(p4v - mn);
    l = fmaf(l, sc, (t1 + t2) + (t3 + t4));
    acc.x = fmaf(acc.x, sc, fmaf(t1, m1.x, fmaf(t2, m2.x, fmaf(t3, m3.x, t4 * m4.x))));
    acc.y = fmaf(acc.y, sc, fmaf(t1, m1.y, fmaf(t2, m2.y, fmaf(t3, m3.y, t4 * m4.y))));
    acc.z = fmaf(acc.z, sc, fmaf(t1, m1.z, fmaf(t2, m2.z, fmaf(t3, m3.z, t4 * m4.z))));
    acc.w = fmaf(acc.w, sc, fmaf(t1, m1.w, fmaf(t2, m2.w, fmaf(t3, m3.w, t4 * m4.w))));
    m = mn;
  }
  for (int i = nb * 4; i < cnt; ++i) {
    int2 v1 = p[i];
    float w1 = __int_as_float(v1.y);
    float4 m1 = *(const float4*)(hl + (size_t)v1.x * 128 + j);
    wsum += w1;
    float p1 = edge_logit(m1, w1, hrd, we4, at4);
    float mn = fmaxf(m, p1);
    float sc = exp2f(m - mn);
    float t1 = exp2f(p1 - mn);
    l = fmaf(l, sc, t1);
    acc.x = fmaf(acc.x, sc, t1 * m1.x);
    acc.y = fmaf(acc.y, sc, t1 * m1.y);
    acc.z = fmaf(acc.z, sc, t1 * m1.z);
    acc.w = fmaf(acc.w, sc, t1 * m1.w);
  }

  float la = wsum / fmaxf((float)cnt, 1.f);
  float4 msgs = *(const float4*)(hl + (size_t)n * 128 + j);
  float ps = edge_logit(msgs, la, hrd, we4, at4);
  float mn = fmaxf(m, ps);
  float sc = exp2f(m - mn);
  float ts = exp2f(ps - mn);
  l = fmaf(l, sc, ts);
  acc.x = fmaf(acc.x, sc, ts * msgs.x);
  acc.y = fmaf(acc.y, sc, ts * msgs.y);
  acc.z = fmaf(acc.z, sc, ts * msgs.z);
  acc.w = fmaf(acc.w, sc, ts * msgs.w);

  float inv = 1.f / l;
  float4 b4 = *(const float4*)(bias + j);
  float4 o;
  o.x = fmaxf(fmaf(acc.x, inv, b4.x), 0.f);
  o.y = fmaxf(fmaf(acc.y, inv, b4.y), 0.f);
  o.z = fmaxf(fmaf(acc.z, inv, b4.z), 0.f);
  o.w = fmaxf(fmaf(acc.w, inv, b4.w), 0.f);
  *(float4*)(out + (size_t)n * 128 + j) = o;
}

// ---------- pool (batch is sorted): 64 rows/block ----------
__global__ __launch_bounds__(128) void pool_kernel(
    const float* __restrict__ h, const int* __restrict__ batch,
    float* __restrict__ pooled)
{
  int n0 = blockIdx.x * 64;
  if (n0 >= NN) return;
  int j = threadIdx.x;
  int nend = n0 + 64; if (nend > NN) nend = NN;
  float acc = 0.f;
  int curb = batch[n0];
  for (int n = n0; n < nend; ++n) {
    int b = batch[n];
    if (b != curb) {
      unsafeAtomicAdd(pooled + curb * 128 + j, acc);
      acc = 0.f; curb = b;
    }
    acc += h[(size_t)n * 128 + j];
  }
  unsafeAtomicAdd(pooled + curb * 128 + j, acc);
}

// ---------- fc ----------
__global__ __launch_bounds__(128) void fc_kernel(
    const float* __restrict__ pooled, const float* __restrict__ fcw,
    const float* __restrict__ fcb, float* __restrict__ out)
{
  int b = blockIdx.x;
  int t = threadIdx.x;
  float v = pooled[b * 128 + t] * fcw[t];
#pragma unroll
  for (int off = 32; off >= 1; off >>= 1) v += __shfl_down(v, off, 64);
  __shared__ float sbuf[2];
  if ((t & 63) == 0) sbuf[t >> 6] = v;
  __syncthreads();
  if (t == 0) out[b] = sbuf[0] + sbuf[1] + fcb[0];
}

extern "C" void kernel_launch(void* const* d_in, const int* in_sizes, int n_in,
                              void* d_out, int out_size, void* d_ws, size_t ws_size,
                              hipStream_t stream)
{
  const float* x    = (const float*)d_in[0];
  const int*   ei   = (const int*)d_in[1];
  const float* ea   = (const float*)d_in[2];
  const int*   batch= (const int*)d_in[3];
  const float* c1w  = (const float*)d_in[4];
  const float* c1b  = (const float*)d_in[5];
  const float* c2w  = (const float*)d_in[6];
  const float* c2b  = (const float*)d_in[7];
  const float* gWl[2] = { (const float*)d_in[8],  (const float*)d_in[13] };
  const float* gWr[2] = { (const float*)d_in[9],  (const float*)d_in[14] };
  const float* gWe[2] = { (const float*)d_in[10], (const float*)d_in[15] };
  const float* gAt[2] = { (const float*)d_in[11], (const float*)d_in[16] };
  const float* gB [2] = { (const float*)d_in[12], (const float*)d_in[17] };
  const float* fcw  = (const float*)d_in[18];
  const float* fcb  = (const float*)d_in[19];
  float* out = (float*)d_out;

  const int* src = ei;
  const int* dst = ei + EE;

  float* ws = (float*)d_ws;
  float* h0      = ws;                         // 12,800,000 f
  float* hl      = h0 + 12800000;              // 12,800,000 f
  float* hr      = hl + 12800000;              // 12,800,000 f
  int2*  pack    = (int2*)(hr + 12800000);     // NN*CAP int2
  int*   cursor  = (int*)(pack + (size_t)NN * CAP); // 100,000 i
  float* pooled  = (float*)(cursor + NN);      // 8,192 f
  unsigned short* wtH = (unsigned short*)(pooled + 8192);  // 2*256*128 ushort
  unsigned short* wtL = wtH + 2 * 256 * 128;

  hipMemsetAsync(cursor, 0, NN * sizeof(int), stream);
  hipMemsetAsync(pooled, 0, BB * 128 * sizeof(float), stream);

  conv_kernel<<<(NN + 15) / 16, 256, 0, stream>>>(x, c1w, c1b, c2w, c2b, h0);
  prep_w<<<512, 128, 0, stream>>>(gWl[0], gWr[0], gWl[1], gWr[1], wtH, wtL);
  scatter_pad<<<(EE + 255) / 256, 256, 0, stream>>>(src, dst, ea, cursor, pack);

  for (int L = 0; L < 2; ++L) {
    gemm_mfma<<<(NN + 127) / 128, 256, 0, stream>>>(
        h0, wtH + (size_t)L * 256 * 128, wtL + (size_t)L * 256 * 128, hl, hr);
    gat_node_kernel<<<(NN + 7) / 8, 256, 0, stream>>>(cursor, pack, hl, hr,
                                                      gWe[L], gAt[L], gB[L], h0);
  }

  pool_kernel<<<(NN + 63) / 64, 128, 0, stream>>>(h0, batch, pooled);
  fc_kernel<<<BB, 128, 0, stream>>>(pooled, fcw, fcb, out);
}

// Round 14
// 820.088 us; speedup vs baseline: 1.3330x; 1.3330x over previous
//
#include <hip/hip_runtime.h>
#include <math.h>

#define NN 100000
#define EE 1600000
#define BB 64
#define CAP 48   // max in-degree; deg ~ Poisson(16), P(deg>=48) ~ 2e-10

typedef __attribute__((ext_vector_type(8))) short bf16x8;   // 8 bf16 (4 VGPRs)
typedef __attribute__((ext_vector_type(4))) float f32x4;    // 4 fp32 acc

__device__ __forceinline__ float lrelu(float v) { return v > 0.f ? v : 0.2f * v; }

// ---------- temporal conv: x[N,1,35] -> h0[N,128] (16 nodes x 16 thr) ----------
__global__ __launch_bounds__(256) void conv_kernel(
    const float* __restrict__ x,
    const float* __restrict__ w1, const float* __restrict__ b1,
    const float* __restrict__ w2, const float* __restrict__ b2,
    float* __restrict__ h0)
{
  __shared__ float s_x[16 * 35];
  __shared__ float s_c1[16 * 49];
  __shared__ float s_w2[16 * 49];
  __shared__ float s_w1[48], s_b1[16], s_b2[16];
  int tid = threadIdx.x;
  int n0 = blockIdx.x * 16;
  for (int i = tid; i < 16 * 35; i += 256) s_x[i] = x[(size_t)n0 * 35 + i];
  if (tid < 48) s_w1[tid] = w1[tid];
  if (tid < 16) { s_b1[tid] = b1[tid]; s_b2[tid] = b2[tid]; }
  for (int i = tid; i < 768; i += 256) s_w2[(i / 48) * 49 + (i % 48)] = w2[i];
  __syncthreads();

  int node = tid >> 4;
  int lane = tid & 15;
  const float* row = s_x + node * 35;
  float* c1n = s_c1 + node * 49;
  float acc8[8];

  for (int t = 0; t < 8; ++t) {
#pragma unroll
    for (int k = 0; k < 3; ++k) {
      int base = 4 * t + 2 * k;
      float a = s_b1[lane] + s_w1[lane * 3] * row[base]
                           + s_w1[lane * 3 + 1] * row[base + 1]
                           + s_w1[lane * 3 + 2] * row[base + 2];
      c1n[lane * 3 + k] = a > 0.f ? a : 0.f;
    }
    __syncthreads();
    float acc = s_b2[lane];
    const float* w2r = s_w2 + lane * 49;
#pragma unroll
    for (int i = 0; i < 48; ++i) acc += w2r[i] * c1n[i];
    acc8[t] = fmaxf(acc, 0.f);
    __syncthreads();
  }

  float* o = h0 + (size_t)(n0 + node) * 128 + lane * 8;
  float4 o0 = { acc8[0], acc8[1], acc8[2], acc8[3] };
  float4 o1 = { acc8[4], acc8[5], acc8[6], acc8[7] };
  *(float4*)o = o0;
  *(float4*)(o + 4) = o1;
}

// ---------- padded-CSR scatter: 1 edge/thread (measured-best shape) ----------
__global__ void scatter_pad(const int* __restrict__ src, const int* __restrict__ dst,
                            const float* __restrict__ ea,
                            int* __restrict__ cursor, int2* __restrict__ pack)
{
  int e = blockIdx.x * blockDim.x + threadIdx.x;
  if (e >= EE) return;
  int d = dst[e];
  int pos = atomicAdd(cursor + d, 1);
  if (pos < CAP)
    pack[(size_t)d * CAP + pos] = make_int2(src[e], __float_as_int(ea[e]));
}

// ---------- W prep: [Wl|Wr] fp32 -> transposed bf16 hi/lo  Wt[n(256)][k(128)] ----------
__global__ __launch_bounds__(128) void prep_w(
    const float* __restrict__ Wl0, const float* __restrict__ Wr0,
    const float* __restrict__ Wl1, const float* __restrict__ Wr1,
    unsigned short* __restrict__ wtH, unsigned short* __restrict__ wtL)
{
  int bx = blockIdx.x;              // layer*256 + n
  int layer = bx >> 8;
  int n = bx & 255;
  const float* W = (layer == 0) ? ((n < 128) ? Wl0 : Wr0)
                                : ((n < 128) ? Wl1 : Wr1);
  int nn = n & 127;
  int k = threadIdx.x;
  float v = W[k * 128 + nn];
  unsigned b = __float_as_uint(v);
  unsigned short hi = (unsigned short)(b >> 16);
  float hv = __uint_as_float(b & 0xffff0000u);
  float lv = v - hv;                               // exact
  unsigned short lo = (unsigned short)(__float_as_uint(lv) >> 16);
  wtH[(size_t)bx * 128 + k] = hi;
  wtL[(size_t)bx * 128 + k] = lo;
}

// ---------- MFMA dual GEMM v2 (bf16x3 split = fp32-accurate) ----------
// 1563 blocks x 256 thr; wave w owns rows blk*64 + w*16 (one m-tile), all 256 cols.
// acc fully unrolled -> 16 f32x4 fragments in registers (no scratch).
__global__ __launch_bounds__(256) void gemm_mfma(
    const float* __restrict__ A,
    const unsigned short* __restrict__ wtH, const unsigned short* __restrict__ wtL,
    float* __restrict__ Cl, float* __restrict__ Cr)
{
  int tid = threadIdx.x;
  int l = tid & 63;
  int w = tid >> 6;
  int lm = l & 15;                 // m (A rows) / n (B) / col (C) within tile
  int quad = l >> 4;
  int lk = quad * 8;               // k offset within 32-chunk
  int row = blockIdx.x * 64 + w * 16 + lm;
  int rA = row < NN ? row : 0;     // clamp loads; stores guarded

  f32x4 acc[16];
  f32x4 z = { 0.f, 0.f, 0.f, 0.f };
#pragma unroll
  for (int nt = 0; nt < 16; ++nt) acc[nt] = z;

#pragma unroll
  for (int k0 = 0; k0 < 128; k0 += 32) {
    int kb = k0 + lk;
    const float* pA = A + (size_t)rA * 128 + kb;
    float4 a0 = *(const float4*)pA;
    float4 a1 = *(const float4*)(pA + 4);
    float va[8] = { a0.x, a0.y, a0.z, a0.w, a1.x, a1.y, a1.z, a1.w };
    bf16x8 aH, aL;
#pragma unroll
    for (int j = 0; j < 8; ++j) {
      unsigned ba = __float_as_uint(va[j]);
      aH[j] = (short)(ba >> 16);
      float lf = va[j] - __uint_as_float(ba & 0xffff0000u);
      aL[j] = (short)(__float_as_uint(lf) >> 16);
    }
#pragma unroll
    for (int nt = 0; nt < 16; ++nt) {
      const unsigned short* ph = wtH + (size_t)(nt * 16 + lm) * 128 + kb;
      const unsigned short* pl = wtL + (size_t)(nt * 16 + lm) * 128 + kb;
      bf16x8 bh = *(const bf16x8*)ph;
      bf16x8 bl = *(const bf16x8*)pl;
      acc[nt] = __builtin_amdgcn_mfma_f32_16x16x32_bf16(aH, bh, acc[nt], 0, 0, 0);
      acc[nt] = __builtin_amdgcn_mfma_f32_16x16x32_bf16(aH, bl, acc[nt], 0, 0, 0);
      acc[nt] = __builtin_amdgcn_mfma_f32_16x16x32_bf16(aL, bh, acc[nt], 0, 0, 0);
    }
  }

  // epilogue: C/D layout col=lane&15, row=quad*4+reg  [m89-verified]
  int mbase = blockIdx.x * 64 + w * 16 + quad * 4;
#pragma unroll
  for (int nt = 0; nt < 16; ++nt) {
    int col = nt * 16 + lm;
    float* Cb = (col < 128) ? Cl : Cr;
    int cc = col & 127;
#pragma unroll
    for (int r = 0; r < 4; ++r) {
      int rr = mbase + r;
      if (rr < NN) Cb[(size_t)rr * 128 + cc] = acc[nt][r];
    }
  }
}

// ---------- fused GAT node kernel ----------
// 32 lanes/node, log2-domain logits (exp2), 4-edge blocks with 1-ahead pipeline
__device__ __forceinline__ float edge_logit(float4 msg, float w,
                                            float4 hrd, float4 we4, float4 at4)
{
  float s0 = lrelu(fmaf(w, we4.x, hrd.x) + msg.x);
  float s1 = lrelu(fmaf(w, we4.y, hrd.y) + msg.y);
  float s2 = lrelu(fmaf(w, we4.z, hrd.z) + msg.z);
  float s3 = lrelu(fmaf(w, we4.w, hrd.w) + msg.w);
  float p = fmaf(s0, at4.x, fmaf(s1, at4.y, fmaf(s2, at4.z, s3 * at4.w)));
  p += __shfl_xor(p, 1, 8);
  p += __shfl_xor(p, 2, 8);
  p += __shfl_xor(p, 4, 8);
  return p;
}

__global__ __launch_bounds__(256) void gat_node_kernel(
    const int* __restrict__ cnt_arr, const int2* __restrict__ pack,
    const float* __restrict__ hl, const float* __restrict__ hr,
    const float* __restrict__ We, const float* __restrict__ att,
    const float* __restrict__ bias, float* __restrict__ out)
{
  int n = blockIdx.x * 8 + (threadIdx.x >> 5);
  if (n >= NN) return;
  int lq = threadIdx.x & 31;
  int j = lq * 4;
  float4 hrd = *(const float4*)(hr + (size_t)n * 128 + j);
  float4 we4 = *(const float4*)(We + j);
  float4 at4 = *(const float4*)(att + j);
  const float RLN2 = 1.44269504088896340736f;
  at4.x *= RLN2; at4.y *= RLN2; at4.z *= RLN2; at4.w *= RLN2;

  int cnt = cnt_arr[n]; if (cnt > CAP) cnt = CAP;
  const int2* p = pack + (size_t)n * CAP;

  float m = -INFINITY, l = 0.f, wsum = 0.f;
  float4 acc = { 0.f, 0.f, 0.f, 0.f };

  int nb = cnt >> 2;
  int4 ca, cb;
  float4 nr1, nr2, nr3, nr4;
  if (nb > 0) {
    const int4* p4 = (const int4*)p;
    ca = p4[0]; cb = p4[1];
    nr1 = *(const float4*)(hl + (size_t)ca.x * 128 + j);
    nr2 = *(const float4*)(hl + (size_t)ca.z * 128 + j);
    nr3 = *(const float4*)(hl + (size_t)cb.x * 128 + j);
    nr4 = *(const float4*)(hl + (size_t)cb.z * 128 + j);
  }
  for (int b = 0; b < nb; ++b) {
    int4 da = ca, db = cb;
    float4 m1 = nr1, m2 = nr2, m3 = nr3, m4 = nr4;
    if (b + 1 < nb) {
      const int4* p4 = (const int4*)(p + (b + 1) * 4);
      ca = p4[0]; cb = p4[1];
      nr1 = *(const float4*)(hl + (size_t)ca.x * 128 + j);
      nr2 = *(const float4*)(hl + (size_t)ca.z * 128 + j);
      nr3 = *(const float4*)(hl + (size_t)cb.x * 128 + j);
      nr4 = *(const float4*)(hl + (size_t)cb.z * 128 + j);
    }
    float w1 = __int_as_float(da.y), w2 = __int_as_float(da.w);
    float w3 = __int_as_float(db.y), w4 = __int_as_float(db.w);
    wsum += (w1 + w2) + (w3 + w4);
    float p1 = edge_logit(m1, w1, hrd, we4, at4);
    float p2 = edge_logit(m2, w2, hrd, we4, at4);
    float p3 = edge_logit(m3, w3, hrd, we4, at4);
    float p4v = edge_logit(m4, w4, hrd, we4, at4);
    float mn = fmaxf(fmaxf(m, fmaxf(p1, p2)), fmaxf(p3, p4v));
    float sc = exp2f(m - mn);
    float t1 = exp2f(p1 - mn);
    float t2 = exp2f(p2 - mn);
    float t3 = exp2f(p3 - mn);
    float t4 = exp2f(p4v - mn);
    l = fmaf(l, sc, (t1 + t2) + (t3 + t4));
    acc.x = fmaf(acc.x, sc, fmaf(t1, m1.x, fmaf(t2, m2.x, fmaf(t3, m3.x, t4 * m4.x))));
    acc.y = fmaf(acc.y, sc, fmaf(t1, m1.y, fmaf(t2, m2.y, fmaf(t3, m3.y, t4 * m4.y))));
    acc.z = fmaf(acc.z, sc, fmaf(t1, m1.z, fmaf(t2, m2.z, fmaf(t3, m3.z, t4 * m4.z))));
    acc.w = fmaf(acc.w, sc, fmaf(t1, m1.w, fmaf(t2, m2.w, fmaf(t3, m3.w, t4 * m4.w))));
    m = mn;
  }
  for (int i = nb * 4; i < cnt; ++i) {
    int2 v1 = p[i];
    float w1 = __int_as_float(v1.y);
    float4 m1 = *(const float4*)(hl + (size_t)v1.x * 128 + j);
    wsum += w1;
    float p1 = edge_logit(m1, w1, hrd, we4, at4);
    float mn = fmaxf(m, p1);
    float sc = exp2f(m - mn);
    float t1 = exp2f(p1 - mn);
    l = fmaf(l, sc, t1);
    acc.x = fmaf(acc.x, sc, t1 * m1.x);
    acc.y = fmaf(acc.y, sc, t1 * m1.y);
    acc.z = fmaf(acc.z, sc, t1 * m1.z);
    acc.w = fmaf(acc.w, sc, t1 * m1.w);
  }

  float la = wsum / fmaxf((float)cnt, 1.f);
  float4 msgs = *(const float4*)(hl + (size_t)n * 128 + j);
  float ps = edge_logit(msgs, la, hrd, we4, at4);
  float mn = fmaxf(m, ps);
  float sc = exp2f(m - mn);
  float ts = exp2f(ps - mn);
  l = fmaf(l, sc, ts);
  acc.x = fmaf(acc.x, sc, ts * msgs.x);
  acc.y = fmaf(acc.y, sc, ts * msgs.y);
  acc.z = fmaf(acc.z, sc, ts * msgs.z);
  acc.w = fmaf(acc.w, sc, ts * msgs.w);

  float inv = 1.f / l;
  float4 b4 = *(const float4*)(bias + j);
  float4 o;
  o.x = fmaxf(fmaf(acc.x, inv, b4.x), 0.f);
  o.y = fmaxf(fmaf(acc.y, inv, b4.y), 0.f);
  o.z = fmaxf(fmaf(acc.z, inv, b4.z), 0.f);
  o.w = fmaxf(fmaf(acc.w, inv, b4.w), 0.f);
  *(float4*)(out + (size_t)n * 128 + j) = o;
}

// ---------- pool (batch is sorted): 64 rows/block ----------
__global__ __launch_bounds__(128) void pool_kernel(
    const float* __restrict__ h, const int* __restrict__ batch,
    float* __restrict__ pooled)
{
  int n0 = blockIdx.x * 64;
  if (n0 >= NN) return;
  int j = threadIdx.x;
  int nend = n0 + 64; if (nend > NN) nend = NN;
  float acc = 0.f;
  int curb = batch[n0];
  for (int n = n0; n < nend; ++n) {
    int b = batch[n];
    if (b != curb) {
      unsafeAtomicAdd(pooled + curb * 128 + j, acc);
      acc = 0.f; curb = b;
    }
    acc += h[(size_t)n * 128 + j];
  }
  unsafeAtomicAdd(pooled + curb * 128 + j, acc);
}

// ---------- fc ----------
__global__ __launch_bounds__(128) void fc_kernel(
    const float* __restrict__ pooled, const float* __restrict__ fcw,
    const float* __restrict__ fcb, float* __restrict__ out)
{
  int b = blockIdx.x;
  int t = threadIdx.x;
  float v = pooled[b * 128 + t] * fcw[t];
#pragma unroll
  for (int off = 32; off >= 1; off >>= 1) v += __shfl_down(v, off, 64);
  __shared__ float sbuf[2];
  if ((t & 63) == 0) sbuf[t >> 6] = v;
  __syncthreads();
  if (t == 0) out[b] = sbuf[0] + sbuf[1] + fcb[0];
}

extern "C" void kernel_launch(void* const* d_in, const int* in_sizes, int n_in,
                              void* d_out, int out_size, void* d_ws, size_t ws_size,
                              hipStream_t stream)
{
  const float* x    = (const float*)d_in[0];
  const int*   ei   = (const int*)d_in[1];
  const float* ea   = (const float*)d_in[2];
  const int*   batch= (const int*)d_in[3];
  const float* c1w  = (const float*)d_in[4];
  const float* c1b  = (const float*)d_in[5];
  const float* c2w  = (const float*)d_in[6];
  const float* c2b  = (const float*)d_in[7];
  const float* gWl[2] = { (const float*)d_in[8],  (const float*)d_in[13] };
  const float* gWr[2] = { (const float*)d_in[9],  (const float*)d_in[14] };
  const float* gWe[2] = { (const float*)d_in[10], (const float*)d_in[15] };
  const float* gAt[2] = { (const float*)d_in[11], (const float*)d_in[16] };
  const float* gB [2] = { (const float*)d_in[12], (const float*)d_in[17] };
  const float* fcw  = (const float*)d_in[18];
  const float* fcb  = (const float*)d_in[19];
  float* out = (float*)d_out;

  const int* src = ei;
  const int* dst = ei + EE;

  float* ws = (float*)d_ws;
  float* h0      = ws;                         // 12,800,000 f
  float* hl      = h0 + 12800000;              // 12,800,000 f
  float* hr      = hl + 12800000;              // 12,800,000 f
  int2*  pack    = (int2*)(hr + 12800000);     // NN*CAP int2
  int*   cursor  = (int*)(pack + (size_t)NN * CAP); // 100,000 i
  float* pooled  = (float*)(cursor + NN);      // 8,192 f
  unsigned short* wtH = (unsigned short*)(pooled + 8192);  // 2*256*128 ushort
  unsigned short* wtL = wtH + 2 * 256 * 128;

  hipMemsetAsync(cursor, 0, NN * sizeof(int), stream);
  hipMemsetAsync(pooled, 0, BB * 128 * sizeof(float), stream);

  conv_kernel<<<(NN + 15) / 16, 256, 0, stream>>>(x, c1w, c1b, c2w, c2b, h0);
  prep_w<<<512, 128, 0, stream>>>(gWl[0], gWr[0], gWl[1], gWr[1], wtH, wtL);
  scatter_pad<<<(EE + 255) / 256, 256, 0, stream>>>(src, dst, ea, cursor, pack);

  for (int L = 0; L < 2; ++L) {
    gemm_mfma<<<(NN + 63) / 64, 256, 0, stream>>>(
        h0, wtH + (size_t)L * 256 * 128, wtL + (size_t)L * 256 * 128, hl, hr);
    gat_node_kernel<<<(NN + 7) / 8, 256, 0, stream>>>(cursor, pack, hl, hr,
                                                      gWe[L], gAt[L], gB[L], h0);
  }

  pool_kernel<<<(NN + 63) / 64, 128, 0, stream>>>(h0, batch, pooled);
  fc_kernel<<<BB, 128, 0, stream>>>(pooled, fcw, fcb, out);
}